// Round 6
// baseline (7013.568 us; speedup 1.0000x reference)
//
#include <hip/hip_runtime.h>

#define NGRAPH  1024
#define E_EDGES 2097152
#define ECAP    2944
#define MAXZ    1000
#define XS      65      // padded LDS row stride: bank = (r + c) % 32 -> 2-way max (free)

__device__ __forceinline__ float bfu(unsigned short u) {
    return __uint_as_float(((unsigned int)u) << 16);
}
__device__ __forceinline__ unsigned short f2bfu_rne(float f) {
    unsigned int x = __float_as_uint(f);
    unsigned int r = (x + 0x7FFFu + ((x >> 16) & 1u)) >> 16;
    return (unsigned short)r;
}

// ---------------- diagnostics (removed once green) ----------------

__global__ void markA_kernel(float* out) {
    int i = blockIdx.x * 256 + threadIdx.x;
    if (i < NGRAPH) out[i] = 4.0f;
}
__global__ void markWS_kernel(float* out) {
    int i = blockIdx.x * 256 + threadIdx.x;
    if (i < NGRAPH) out[i] = 2.0f;
}
__global__ void markB_kernel(const unsigned* goff, float* out) {
    int i = blockIdx.x * 256 + threadIdx.x;
    if (i < NGRAPH) out[i] = 8.0f + (float)goff[NGRAPH] * 1e-7f;
}

// ---------------- preprocessing: group edges by graph ----------------

__global__ void init_kernel(unsigned* cnt, unsigned* fill) {
    int i = blockIdx.x * 256 + threadIdx.x;
    if (i < NGRAPH) { cnt[i] = 0u; fill[i] = 0u; }
}

__global__ void count_kernel(const int* ei, unsigned* cnt) {
    int e = blockIdx.x * 256 + threadIdx.x;
    if (e < E_EDGES) atomicAdd(&cnt[ei[e] >> 7], 1u);
}

__global__ void scan_kernel(const unsigned* cnt, unsigned* goff) {
    __shared__ unsigned s[NGRAPH];
    int t = threadIdx.x;
    for (int i = t; i < NGRAPH; i += 256) s[i] = cnt[i];
    __syncthreads();
    if (t == 0) {
        unsigned run = 0;
        for (int i = 0; i < NGRAPH; ++i) { unsigned c = s[i]; s[i] = run; run += c; }
        goff[NGRAPH] = run;
    }
    __syncthreads();
    for (int i = t; i < NGRAPH; i += 256) goff[i] = s[i];
}

__global__ void scatter_kernel(const int* ei, const unsigned* goff,
                               unsigned* fill, unsigned short* edges) {
    int e = blockIdx.x * 256 + threadIdx.x;
    if (e >= E_EDGES) return;
    int s = ei[e];
    int d = ei[E_EDGES + e];
    int g = s >> 7;
    unsigned pos = goff[g] + atomicAdd(&fill[g], 1u);
    edges[pos] = (unsigned short)((s & 127) | ((d & 127) << 8));
}

// ---------------- fused per-graph GNN + sort-pool + CNN/MLP head ----------------
// All float inputs are FLOAT32 (bf16-rounded values stored as f32).

__global__ void gnn_kernel(
    const int* z, const unsigned* goff, const unsigned short* edges,
    const float* zt,
    const float* W0, const float* b0,
    const float* W1, const float* b1,
    const float* W2, const float* b2,
    const float* W3, const float* b3,
    const float* c1w, const float* c1b,
    const float* c2w, const float* c2b,
    const float* l1w, const float* l1b,
    const float* l2w, const float* l2b,
    float* out)
{
    __shared__ float          Xhi[128 * XS];   // 33280 B (reused as td[5790] for the head)
    __shared__ float          XloF[4160];      // 16640 B (u16 lo-words; reused by head tmps)
    __shared__ unsigned char  csr[ECAP];       //  2944 B
    __shared__ unsigned short rp16[132];
    __shared__ int            aux[128];        // degree, then rank
    __shared__ double         keyd[128];
    __shared__ double         h4s[128];

    unsigned short* Xlo = (unsigned short*)XloF;

    const int g  = blockIdx.x;
    const int t  = threadIdx.x;     // 0..255
    const int r  = t >> 1;          // node row 0..127
    const int c0 = (t & 1) * 32;    // channel base 0 or 32

    if (t < 128) aux[t] = 0;
    __syncthreads();

    // in-degree count
    const unsigned e0 = goff[g], e1 = goff[g + 1];
    for (unsigned e = e0 + t; e < e1; e += 256)
        atomicAdd(&aux[(edges[e] >> 8) & 127], 1);
    __syncthreads();

    // exclusive scan over 128 nodes (thread 0; trivial cost)
    if (t == 0) {
        unsigned run = 0;
        for (int i = 0; i < 128; ++i) {
            rp16[i] = (unsigned short)run;
            run += (unsigned)aux[i];
        }
        rp16[128] = (unsigned short)run;
    }
    __syncthreads();
    const int mydeg = (t < 128) ? aux[t] : 0;     // keep in-degree before aux reuse
    const int rowdeg = aux[r];
    __syncthreads();
    if (t < 128) aux[t] = 0;
    __syncthreads();

    // CSR scatter (dest-major, duplicates kept)
    for (unsigned e = e0 + t; e < e1; e += 256) {
        unsigned short ev = edges[e];
        int s = ev & 127, d = (ev >> 8) & 127;
        unsigned pos = (unsigned)rp16[d] + (unsigned)atomicAdd(&aux[d], 1);
        if (pos < ECAP) csr[pos] = (unsigned char)s;
    }
    // X0 = z_table[z]  (f32 exact; lo = 0)
    for (int idx = t; idx < 8192; idx += 256) {
        int n = idx >> 6, c = idx & 63;
        int zv = z[(g << 7) + n];
        zv = (zv < 0) ? 0 : ((zv >= MAXZ) ? MAXZ - 1 : zv);
        Xhi[n * XS + c] = zt[zv * 64 + c];
        Xlo[n * XS + c] = 0;
    }
    __syncthreads();

    const double dvr = 1.0 / sqrt((double)(rowdeg + 1));

    // ---- three GCN layers (fp64 via hi/lo-compensated LDS state) ----
    float arch[3][32];
    for (int layer = 0; layer < 3; ++layer) {
        const float* Wg = (layer == 0) ? W0 : (layer == 1) ? W1 : W2;
        const float* bg = (layer == 0) ? b0 : (layer == 1) ? b1 : b2;

        // phase 1: H[r] = dinv[r] * (X @ W)[r]  for channels c0..c0+31
        double accd[32]; float accf[32];
        for (int j = 0; j < 32; ++j) { accd[j] = 0.0; accf[j] = 0.f; }
        for (int k = 0; k < 64; ++k) {
            double xd = (double)Xhi[r * XS + k];
            float  xl = bfu(Xlo[r * XS + k]);
            const float* wrow = &Wg[k * 64 + c0];
#pragma unroll 8
            for (int j = 0; j < 32; ++j) {
                float w = wrow[j];
                accd[j] += xd * (double)w;
                accf[j] = fmaf(xl, w, accf[j]);
            }
        }
        __syncthreads();          // all X reads done before overwrite
        for (int j = 0; j < 32; ++j) {
            double h = dvr * (accd[j] + (double)accf[j]);
            float hf = (float)h;
            Xhi[r * XS + c0 + j] = hf;
            Xlo[r * XS + c0 + j] = f2bfu_rne((float)(h - (double)hf));
        }
        __syncthreads();          // H fully written

        // phase 2: agg[r] = H[r] + sum_{s in csr(r)} H[s]
        double ad[32]; float af[32];
        for (int j = 0; j < 32; ++j) {
            ad[j] = (double)Xhi[r * XS + c0 + j];
            af[j] = bfu(Xlo[r * XS + c0 + j]);
        }
        for (unsigned e = rp16[r]; e < rp16[r + 1]; ++e) {
            int s = csr[e];
            const float*          hp = &Xhi[s * XS + c0];
            const unsigned short* lp = &Xlo[s * XS + c0];
#pragma unroll 8
            for (int j = 0; j < 32; ++j) {
                ad[j] += (double)hp[j];
                af[j] += bfu(lp[j]);
            }
        }
        __syncthreads();          // all H reads done before overwrite
        for (int j = 0; j < 32; ++j) {
            double v = tanh(dvr * (ad[j] + (double)af[j]) + (double)bg[c0 + j]);
            float vf = (float)v;
            arch[layer][j] = vf;
            Xhi[r * XS + c0 + j] = vf;
            Xlo[r * XS + c0 + j] = f2bfu_rne((float)(v - (double)vf));
        }
        __syncthreads();
    }

    // ---- layer 4 (64 -> 1): key = tanh(dinv*(h4[d] + sum_adj h4[s]) + b3) ----
    if (t < 128) {
        double sd = 0.0; float sf = 0.f;
        for (int k = 0; k < 64; ++k) {
            float w = W3[k];
            sd += (double)Xhi[t * XS + k] * (double)w;
            sf = fmaf(bfu(Xlo[t * XS + k]), w, sf);
        }
        h4s[t] = (1.0 / sqrt((double)(mydeg + 1))) * (sd + (double)sf);
    }
    __syncthreads();
    if (t < 128) {
        double a = h4s[t];
        for (unsigned e = rp16[t]; e < rp16[t + 1]; ++e) a += h4s[csr[e]];
        keyd[t] = tanh((1.0 / sqrt((double)(mydeg + 1))) * a + (double)b3[0]);
    }
    __syncthreads();

    // stable descending rank (ties -> lower index) == stable argsort(-key)
    if (t < 128) {
        double kv = keyd[t];
        int rk = 0;
        for (int j = 0; j < 128; ++j) {
            double kj = keyd[j];
            if (kj > kv || (kj == kv && j < t)) ++rk;
        }
        aux[t] = rk;
    }
    __syncthreads();

    // ---- sort-pool into td (reuse Xhi) ----
    float* td = Xhi;
    {
        int rk = aux[r];
        if (rk < 30) {
            for (int l = 0; l < 3; ++l)
                for (int j = 0; j < 32; ++j)
                    td[rk * 193 + l * 64 + c0 + j] = arch[l][j];
        }
    }
    if (t < 128) {
        int rk = aux[t];
        if (rk < 30) td[rk * 193 + 192] = (float)keyd[t];
    }
    __syncthreads();

    // ---- head (f32; weights from global, L1-cached) ----
    float* h1v = XloF;          // 480
    float* ppv = XloF + 480;    // 240
    float* flv = XloF + 720;    // 352
    float* hmv = XloF + 1072;   // 128

    // conv1: per-node linear 193->16, relu
    for (int idx = t; idx < 480; idx += 256) {
        int c = idx & 15, k = idx >> 4;
        float s = c1b[c];
        for (int d = 0; d < 193; ++d) s = fmaf(td[k * 193 + d], c1w[c * 193 + d], s);
        h1v[c * 30 + k] = s > 0.f ? s : 0.f;
    }
    __syncthreads();
    // maxpool(2,2): [16,30] -> [16,15]
    for (int idx = t; idx < 240; idx += 256) {
        int c = idx & 15, i = idx >> 4;
        float a = h1v[c * 30 + 2 * i], b = h1v[c * 30 + 2 * i + 1];
        ppv[c * 15 + i] = a > b ? a : b;
    }
    __syncthreads();
    // conv2: 16->32, k=5, valid, relu
    for (int idx = t; idx < 352; idx += 256) {
        int o = idx / 11, j = idx % 11;
        float s = c2b[o];
        for (int i = 0; i < 16; ++i)
#pragma unroll
            for (int u = 0; u < 5; ++u)
                s = fmaf(ppv[i * 15 + j + u], c2w[o * 80 + i * 5 + u], s);
        flv[idx] = s > 0.f ? s : 0.f;
    }
    __syncthreads();
    // lin1: 352 -> 128, relu (t-coalesced weight reads)
    if (t < 128) {
        float s = l1b[t];
        for (int i = 0; i < 352; ++i) s = fmaf(flv[i], l1w[i * 128 + t], s);
        hmv[t] = s > 0.f ? s : 0.f;
    }
    __syncthreads();
    // lin2: 128 -> 1
    if (t == 0) {
        float s = l2b[0];
        for (int m = 0; m < 128; ++m) s = fmaf(hmv[m], l2w[m], s);
        out[g] = s;
    }
}

// ---------------- launch ----------------

extern "C" void kernel_launch(void* const* d_in, const int* in_sizes, int n_in,
                              void* d_out, int out_size, void* d_ws, size_t ws_size,
                              hipStream_t stream) {
    const int*   z   = (const int*)d_in[0];
    const int*   ei  = (const int*)d_in[1];
    const float* zt  = (const float*)d_in[3];
    const float* W0  = (const float*)d_in[4];
    const float* b0  = (const float*)d_in[5];
    const float* W1  = (const float*)d_in[6];
    const float* b1  = (const float*)d_in[7];
    const float* W2  = (const float*)d_in[8];
    const float* b2  = (const float*)d_in[9];
    const float* W3  = (const float*)d_in[10];
    const float* b3  = (const float*)d_in[11];
    const float* c1w = (const float*)d_in[12];
    const float* c1b = (const float*)d_in[13];
    const float* c2w = (const float*)d_in[14];
    const float* c2b = (const float*)d_in[15];
    const float* l1w = (const float*)d_in[16];
    const float* l1b = (const float*)d_in[17];
    const float* l2w = (const float*)d_in[18];
    const float* l2b = (const float*)d_in[19];
    float* out = (float*)d_out;

    markA_kernel<<<4, 256, 0, stream>>>(out);

    const size_t NEEDED = 16384 + (size_t)E_EDGES * 2;   // 4,210,688 B
    if (ws_size < NEEDED) {
        markWS_kernel<<<4, 256, 0, stream>>>(out);
        return;
    }

    char* ws = (char*)d_ws;
    unsigned*       cnt   = (unsigned*)ws;                 // 4 KB
    unsigned*       goff  = (unsigned*)(ws + 4096);        // 4.1 KB (8 KB reserved)
    unsigned*       fill  = (unsigned*)(ws + 12288);       // 4 KB
    unsigned short* edges = (unsigned short*)(ws + 16384); // 4 MB

    init_kernel<<<4, 256, 0, stream>>>(cnt, fill);
    count_kernel<<<(E_EDGES + 255) / 256, 256, 0, stream>>>(ei, cnt);
    scan_kernel<<<1, 256, 0, stream>>>(cnt, goff);
    scatter_kernel<<<(E_EDGES + 255) / 256, 256, 0, stream>>>(ei, goff, fill, edges);

    markB_kernel<<<4, 256, 0, stream>>>(goff, out);

    gnn_kernel<<<NGRAPH, 256, 0, stream>>>(z, goff, edges, zt,
                                           W0, b0, W1, b1, W2, b2, W3, b3,
                                           c1w, c1b, c2w, c2b, l1w, l1b, l2w, l2b,
                                           out);
}

// Round 7
// 829.516 us; speedup vs baseline: 8.4550x; 8.4550x over previous
//
#include <hip/hip_runtime.h>

#define NGRAPH  1024
#define E_EDGES 2097152
#define ECAP    2944      // per-graph CSR capacity (mean 2048)
#define NB      16        // scatter sub-buckets per graph
#define CAPB    208       // per-bucket capacity (mean 128, +7 sigma)
#define MAXZ    1000
#define XS      65        // Xhi row stride (floats)
#define LS      33        // Xlo32 row stride (u32 pairs)

__device__ __forceinline__ float bfu_lo(unsigned u) {   // low 16 bits as bf16 -> f32
    return __uint_as_float(u << 16);
}
__device__ __forceinline__ float bfu_hi(unsigned u) {   // high 16 bits as bf16 -> f32
    return __uint_as_float(u & 0xFFFF0000u);
}
__device__ __forceinline__ unsigned packlo(float f0, float f1) {  // truncate-to-bf16 pair
    return (__float_as_uint(f0) >> 16) | (__float_as_uint(f1) & 0xFFFF0000u);
}

// ---------------- diagnostics ----------------
__global__ void markWS_kernel(float* out) {
    int i = blockIdx.x * 256 + threadIdx.x;
    if (i < NGRAPH) out[i] = 2.0f;
}

// ---------------- preprocessing: bucketed edge scatter ----------------

__global__ void initc_kernel(unsigned* ecnt) {
    int i = blockIdx.x * 256 + threadIdx.x;
    if (i < NGRAPH * NB) ecnt[i] = 0u;
}

__global__ void bscatter_kernel(const int* __restrict__ ei,
                                unsigned* __restrict__ ecnt,
                                unsigned short* __restrict__ edges) {
    int e = blockIdx.x * 256 + threadIdx.x;
    if (e >= E_EDGES) return;
    int s = ei[e];
    int d = ei[E_EDGES + e];
    unsigned idx = (unsigned)((s >> 7) * NB + (e & (NB - 1)));
    unsigned pos = atomicAdd(&ecnt[idx], 1u);
    if (pos < CAPB) edges[idx * CAPB + pos] = (unsigned short)((s & 127) | ((d & 127) << 8));
}

// ---------------- fused per-graph GNN + sort-pool + CNN/MLP head ----------------
// 512 threads: row r = t>>2 (0..127), channel base c0 = (t&3)*16.
// X state: hi (f32, stride 65) + lo (bf16-bits packed 2/u32, stride 33); fp64 math.

__global__ __launch_bounds__(512, 2) void gnn_kernel(
    const int* __restrict__ z,
    const unsigned* __restrict__ ecnt, const unsigned short* __restrict__ edges,
    const float* __restrict__ zt,
    const float* __restrict__ W0, const float* __restrict__ b0,
    const float* __restrict__ W1, const float* __restrict__ b1,
    const float* __restrict__ W2, const float* __restrict__ b2,
    const float* __restrict__ W3, const float* __restrict__ b3,
    const float* __restrict__ c1w, const float* __restrict__ c1b,
    const float* __restrict__ c2w, const float* __restrict__ c2b,
    const float* __restrict__ l1w, const float* __restrict__ l1b,
    const float* __restrict__ l2w, const float* __restrict__ l2b,
    float* __restrict__ out)
{
    __shared__ float          Xhi[128 * XS];   // 33280 B (reused as td for the head)
    __shared__ unsigned       Xlo[128 * LS];   // 16896 B (reused for head tmps)
    __shared__ double         Wd[16 * 64];     //  8192 B (weight quarter, f64)
    __shared__ unsigned char  csr[ECAP];       //  2944 B
    __shared__ unsigned short rp16[132];
    __shared__ int            aux[128];        // degree -> cursor -> rank
    __shared__ double         keyd[128];
    __shared__ double         h4s[128];
    __shared__ int            w0tot;

    const int g  = blockIdx.x;
    const int t  = threadIdx.x;       // 0..511
    const int r  = t >> 2;            // row 0..127
    const int c0 = (t & 3) << 4;      // 0,16,32,48

    if (t < 128) aux[t] = 0;
    __syncthreads();

    // in-degree count from buckets
    const unsigned gb = (unsigned)g * NB;
    for (int b = 0; b < NB; ++b) {
        unsigned n = ecnt[gb + b]; if (n > CAPB) n = CAPB;
        const unsigned short* eb = edges + (size_t)(gb + b) * CAPB;
        for (unsigned i = t; i < n; i += 512)
            atomicAdd(&aux[(eb[i] >> 8) & 127], 1);
    }
    __syncthreads();

    const int rowdeg = aux[r];
    const int mydeg  = (t < 128) ? aux[t] : 0;

    // exclusive scan over 128 degrees (two waves, shfl)
    if (t < 128) {
        int v = aux[t];
        for (int o = 1; o < 64; o <<= 1) {
            int u = __shfl_up(v, o, 64);
            if ((t & 63) >= o) v += u;
        }
        if (t == 63) w0tot = v;
        rp16[t + 1] = (unsigned short)v;   // provisional (wave1 fixed below)
    }
    __syncthreads();
    if (t >= 64 && t < 128) rp16[t + 1] = (unsigned short)(rp16[t + 1] + w0tot);
    if (t == 0) rp16[0] = 0;
    if (t < 128) aux[t] = 0;
    __syncthreads();

    // CSR scatter (dest-major, duplicates kept)
    for (int b = 0; b < NB; ++b) {
        unsigned n = ecnt[gb + b]; if (n > CAPB) n = CAPB;
        const unsigned short* eb = edges + (size_t)(gb + b) * CAPB;
        for (unsigned i = t; i < n; i += 512) {
            unsigned short ev = eb[i];
            int s = ev & 127, d = (ev >> 8) & 127;
            unsigned pos = (unsigned)rp16[d] + (unsigned)atomicAdd(&aux[d], 1);
            if (pos < ECAP) csr[pos] = (unsigned char)s;
        }
    }
    // X0 = z_table[z]
    for (int idx = t; idx < 8192; idx += 512) {
        int n = idx >> 6, c = idx & 63;
        int zv = z[(g << 7) + n];
        zv = (zv < 0) ? 0 : ((zv >= MAXZ) ? MAXZ - 1 : zv);
        Xhi[n * XS + c] = zt[zv * 64 + c];
    }
    for (int idx = t; idx < 128 * LS; idx += 512) Xlo[idx] = 0u;
    __syncthreads();

    const double dvr = 1.0 / sqrt((double)(rowdeg + 1));

    // ---- three GCN layers ----
    float arch[3][16];
    for (int layer = 0; layer < 3; ++layer) {
        const float* Wg = (layer == 0) ? W0 : (layer == 1) ? W1 : W2;
        const float* bg = (layer == 0) ? b0 : (layer == 1) ? b1 : b2;

        // phase 1: acc = (X @ W)[r, c0..c0+15], X reconstructed exactly in f64
        double acc[16];
#pragma unroll
        for (int j = 0; j < 16; ++j) acc[j] = 0.0;

        for (int q = 0; q < 4; ++q) {
            __syncthreads();                       // Wd free / X stable
            for (int i = t; i < 1024; i += 512) Wd[i] = (double)Wg[q * 1024 + i];
            __syncthreads();
#pragma unroll
            for (int kk = 0; kk < 16; kk += 2) {
                int k = q * 16 + kk;
                unsigned u = Xlo[r * LS + (k >> 1)];
                double x0 = (double)Xhi[r * XS + k]     + (double)bfu_lo(u);
                double x1 = (double)Xhi[r * XS + k + 1] + (double)bfu_hi(u);
                const double* w0p = &Wd[kk * 64 + c0];
                const double* w1p = &Wd[(kk + 1) * 64 + c0];
#pragma unroll
                for (int j2 = 0; j2 < 8; ++j2) {
                    double2 a = *(const double2*)&w0p[2 * j2];
                    double2 b = *(const double2*)&w1p[2 * j2];
                    acc[2 * j2]     += x0 * a.x + x1 * b.x;
                    acc[2 * j2 + 1] += x0 * a.y + x1 * b.y;
                }
            }
        }
        __syncthreads();                           // all X reads complete

        // H[r] = dinv[r] * acc ; store hi/lo
        float hfv[16], rsv[16];
#pragma unroll
        for (int j = 0; j < 16; ++j) {
            double h = dvr * acc[j];
            hfv[j] = (float)h;
            rsv[j] = (float)(h - (double)hfv[j]);
            Xhi[r * XS + c0 + j] = hfv[j];
        }
#pragma unroll
        for (int j2 = 0; j2 < 8; ++j2)
            Xlo[r * LS + (c0 >> 1) + j2] = packlo(rsv[2 * j2], rsv[2 * j2 + 1]);
        __syncthreads();                           // H fully written

        // phase 2: agg[r] = H[r] + sum_{s in csr(r)} H[s]
        double ad[16]; float af[16];
#pragma unroll
        for (int j = 0; j < 16; ++j) { ad[j] = (double)hfv[j]; af[j] = rsv[j]; }
        for (unsigned e = rp16[r]; e < rp16[r + 1]; ++e) {
            int s = csr[e];
            const float*    hp = &Xhi[s * XS + c0];
            const unsigned* lp = &Xlo[s * LS + (c0 >> 1)];
#pragma unroll
            for (int j2 = 0; j2 < 8; ++j2) {
                unsigned u = lp[j2];
                ad[2 * j2]     += (double)hp[2 * j2];
                ad[2 * j2 + 1] += (double)hp[2 * j2 + 1];
                af[2 * j2]     += bfu_lo(u);
                af[2 * j2 + 1] += bfu_hi(u);
            }
        }
        __syncthreads();                           // all H reads complete

        // X = tanh(dinv*agg + b); archive
#pragma unroll
        for (int j = 0; j < 16; ++j) {
            double v = tanh(dvr * (ad[j] + (double)af[j]) + (double)bg[c0 + j]);
            float vf = (float)v;
            arch[layer][j] = vf;
            hfv[j] = vf;
            rsv[j] = (float)(v - (double)vf);
            Xhi[r * XS + c0 + j] = vf;
        }
#pragma unroll
        for (int j2 = 0; j2 < 8; ++j2)
            Xlo[r * LS + (c0 >> 1) + j2] = packlo(rsv[2 * j2], rsv[2 * j2 + 1]);
        __syncthreads();
    }

    // ---- layer 4 (64 -> 1): key = tanh(dinv*(h4[d] + sum_adj h4[s]) + b3) ----
    if (t < 128) {
        double sd = 0.0;
        for (int k2 = 0; k2 < 32; ++k2) {
            unsigned u = Xlo[t * LS + k2];
            double x0 = (double)Xhi[t * XS + 2 * k2]     + (double)bfu_lo(u);
            double x1 = (double)Xhi[t * XS + 2 * k2 + 1] + (double)bfu_hi(u);
            sd += x0 * (double)W3[2 * k2] + x1 * (double)W3[2 * k2 + 1];
        }
        h4s[t] = (1.0 / sqrt((double)(mydeg + 1))) * sd;
    }
    __syncthreads();
    if (t < 128) {
        double a = h4s[t];
        for (unsigned e = rp16[t]; e < rp16[t + 1]; ++e) a += h4s[csr[e]];
        keyd[t] = tanh((1.0 / sqrt((double)(mydeg + 1))) * a + (double)b3[0]);
    }
    __syncthreads();

    // stable descending rank == stable argsort(-key)
    if (t < 128) {
        double kv = keyd[t];
        int rk = 0;
        for (int j = 0; j < 128; ++j) {
            double kj = keyd[j];
            if (kj > kv || (kj == kv && j < t)) ++rk;
        }
        aux[t] = rk;
    }
    __syncthreads();

    // ---- sort-pool into td (reuse Xhi) ----
    float* td = Xhi;
    {
        int rk = aux[r];
        if (rk < 30) {
#pragma unroll
            for (int l = 0; l < 3; ++l)
#pragma unroll
                for (int j = 0; j < 16; ++j)
                    td[rk * 193 + l * 64 + c0 + j] = arch[l][j];
        }
    }
    if (t < 128) {
        int rk = aux[t];
        if (rk < 30) td[rk * 193 + 192] = (float)keyd[t];
    }
    __syncthreads();

    // ---- head (f32, weights via L1) ----
    float* h1v = (float*)Xlo;          // 480
    float* ppv = (float*)Xlo + 480;    // 240
    float* flv = (float*)Xlo + 720;    // 352
    float* hmv = (float*)Xlo + 1072;   // 128

    if (t < 480) {
        int c = t & 15, k = t >> 4;
        float s = c1b[c];
        for (int d = 0; d < 193; ++d) s = fmaf(td[k * 193 + d], c1w[c * 193 + d], s);
        h1v[c * 30 + k] = s > 0.f ? s : 0.f;
    }
    __syncthreads();
    if (t < 240) {
        int c = t & 15, i = t >> 4;
        float a = h1v[c * 30 + 2 * i], b = h1v[c * 30 + 2 * i + 1];
        ppv[c * 15 + i] = a > b ? a : b;
    }
    __syncthreads();
    if (t < 352) {
        int o = t / 11, j = t % 11;
        float s = c2b[o];
        for (int i = 0; i < 16; ++i)
#pragma unroll
            for (int u = 0; u < 5; ++u)
                s = fmaf(ppv[i * 15 + j + u], c2w[o * 80 + i * 5 + u], s);
        flv[t] = s > 0.f ? s : 0.f;
    }
    __syncthreads();
    if (t < 128) {
        float s = l1b[t];
        for (int i = 0; i < 352; ++i) s = fmaf(flv[i], l1w[i * 128 + t], s);
        hmv[t] = s > 0.f ? s : 0.f;
    }
    __syncthreads();
    if (t < 64) {
        float v = fmaf(hmv[t], l2w[t], hmv[t + 64] * l2w[t + 64]);
#pragma unroll
        for (int o = 32; o > 0; o >>= 1) v += __shfl_down(v, o, 64);
        if (t == 0) out[g] = v + l2b[0];
    }
}

// ---------------- launch ----------------

extern "C" void kernel_launch(void* const* d_in, const int* in_sizes, int n_in,
                              void* d_out, int out_size, void* d_ws, size_t ws_size,
                              hipStream_t stream) {
    const int*   z   = (const int*)d_in[0];
    const int*   ei  = (const int*)d_in[1];
    const float* zt  = (const float*)d_in[3];
    const float* W0  = (const float*)d_in[4];
    const float* b0  = (const float*)d_in[5];
    const float* W1  = (const float*)d_in[6];
    const float* b1  = (const float*)d_in[7];
    const float* W2  = (const float*)d_in[8];
    const float* b2  = (const float*)d_in[9];
    const float* W3  = (const float*)d_in[10];
    const float* b3  = (const float*)d_in[11];
    const float* c1w = (const float*)d_in[12];
    const float* c1b = (const float*)d_in[13];
    const float* c2w = (const float*)d_in[14];
    const float* c2b = (const float*)d_in[15];
    const float* l1w = (const float*)d_in[16];
    const float* l1b = (const float*)d_in[17];
    const float* l2w = (const float*)d_in[18];
    const float* l2b = (const float*)d_in[19];
    float* out = (float*)d_out;

    const size_t ECNT_B = (size_t)NGRAPH * NB * 4;            // 64 KB
    const size_t NEEDED = ECNT_B + (size_t)NGRAPH * NB * CAPB * 2;  // ~6.9 MB
    if (ws_size < NEEDED) {
        markWS_kernel<<<4, 256, 0, stream>>>(out);
        return;
    }

    unsigned*       ecnt  = (unsigned*)d_ws;
    unsigned short* edges = (unsigned short*)((char*)d_ws + ECNT_B);

    initc_kernel<<<(NGRAPH * NB + 255) / 256, 256, 0, stream>>>(ecnt);
    bscatter_kernel<<<(E_EDGES + 255) / 256, 256, 0, stream>>>(ei, ecnt, edges);

    gnn_kernel<<<NGRAPH, 512, 0, stream>>>(z, ecnt, edges, zt,
                                           W0, b0, W1, b1, W2, b2, W3, b3,
                                           c1w, c1b, c2w, c2b, l1w, l1b, l2w, l2b,
                                           out);
}

// Round 8
// 714.675 us; speedup vs baseline: 9.8137x; 1.1607x over previous
//
#include <hip/hip_runtime.h>

#define NGRAPH  1024
#define E_EDGES 2097152
#define ECAP    2944
#define NB      16
#define CAPB    208
#define MAXZ    1000

__device__ __forceinline__ float bfu_lo(unsigned u) { return __uint_as_float(u << 16); }
__device__ __forceinline__ float bfu_hi(unsigned u) { return __uint_as_float(u & 0xFFFF0000u); }
__device__ __forceinline__ unsigned packlo(float f0, float f1) {
    return (__float_as_uint(f0) >> 16) | (__float_as_uint(f1) & 0xFFFF0000u);
}
// XOR-swizzled X indices: conflict-free b128 row access for both r-major and random-s patterns
__device__ __forceinline__ int xh_idx(int r, int k)  { return (r << 6) | (k  ^ ((r & 7) << 3)); }
__device__ __forceinline__ int xl_idx(int r, int k2) { return (r << 5) | (k2 ^ ((r & 7) << 2)); }

__global__ void markWS_kernel(float* out) {
    int i = blockIdx.x * 256 + threadIdx.x;
    if (i < NGRAPH) out[i] = 2.0f;
}

__global__ void bscatter_kernel(const int* __restrict__ ei,
                                unsigned* __restrict__ ecnt,
                                unsigned short* __restrict__ edges) {
    int e = blockIdx.x * 256 + threadIdx.x;
    if (e >= E_EDGES) return;
    int s = ei[e];
    int d = ei[E_EDGES + e];
    unsigned idx = (unsigned)((s >> 7) * NB + (e & (NB - 1)));
    unsigned pos = atomicAdd(&ecnt[idx], 1u);
    if (pos < CAPB) edges[idx * CAPB + pos] = (unsigned short)((s & 127) | ((d & 127) << 8));
}

// 512 threads: thread -> rows {r0, r0+64} (r0 = t>>3), channels c0..c0+7 (c0 = (t&7)*8)
__global__ __launch_bounds__(512, 2) void gnn_kernel(
    const int* __restrict__ z,
    const unsigned* __restrict__ ecnt, const unsigned short* __restrict__ edges,
    const float* __restrict__ zt,
    const float* __restrict__ W0, const float* __restrict__ b0,
    const float* __restrict__ W1, const float* __restrict__ b1,
    const float* __restrict__ W2, const float* __restrict__ b2,
    const float* __restrict__ W3, const float* __restrict__ b3,
    const float* __restrict__ c1w, const float* __restrict__ c1b,
    const float* __restrict__ c2w, const float* __restrict__ c2b,
    const float* __restrict__ l1w, const float* __restrict__ l1b,
    const float* __restrict__ l2w, const float* __restrict__ l2b,
    float* __restrict__ out)
{
    __shared__ float          Xhi[8192];    // 32768 B, swizzled stride 64
    __shared__ unsigned       Xlo[4096];    // 16384 B, bf16 pairs, swizzled stride 32
    __shared__ float          Wf[2048];     //  8192 B, f32 weight half (32 k x 64 j); later G1
    __shared__ unsigned char  csr[ECAP];    //  2944 B
    __shared__ unsigned short rp16[132];
    __shared__ int            aux[128];     // degree -> cursor -> rank
    __shared__ double         keyd[128];
    __shared__ double         h4s[128];
    __shared__ int            inv[30];
    __shared__ int            w0tot;

    const int g  = blockIdx.x;
    const int t  = threadIdx.x;
    const int r0 = t >> 3;
    const int r1 = r0 + 64;
    const int c0 = (t & 7) << 3;

    if (t < 128) aux[t] = 0;
    __syncthreads();

    // in-degree from buckets
    const unsigned gb = (unsigned)g * NB;
    for (int b = 0; b < NB; ++b) {
        unsigned n = ecnt[gb + b]; if (n > CAPB) n = CAPB;
        const unsigned short* eb = edges + (size_t)(gb + b) * CAPB;
        for (unsigned i = t; i < n; i += 512)
            atomicAdd(&aux[(eb[i] >> 8) & 127], 1);
    }
    __syncthreads();

    const int mydeg = (t < 128) ? aux[t] : 0;
    const double dv0 = 1.0 / sqrt((double)(aux[r0] + 1));
    const double dv1 = 1.0 / sqrt((double)(aux[r1] + 1));

    // exclusive scan of degrees (two waves, shfl)
    if (t < 128) {
        int v = aux[t];
        for (int o = 1; o < 64; o <<= 1) {
            int u = __shfl_up(v, o, 64);
            if ((t & 63) >= o) v += u;
        }
        if (t == 63) w0tot = v;
        rp16[t + 1] = (unsigned short)v;
    }
    __syncthreads();
    if (t >= 64 && t < 128) rp16[t + 1] = (unsigned short)(rp16[t + 1] + w0tot);
    if (t == 0) rp16[0] = 0;
    if (t < 128) aux[t] = 0;
    __syncthreads();

    // CSR scatter (dest-major, duplicates kept)
    for (int b = 0; b < NB; ++b) {
        unsigned n = ecnt[gb + b]; if (n > CAPB) n = CAPB;
        const unsigned short* eb = edges + (size_t)(gb + b) * CAPB;
        for (unsigned i = t; i < n; i += 512) {
            unsigned short ev = eb[i];
            int s = ev & 127, d = (ev >> 8) & 127;
            unsigned pos = (unsigned)rp16[d] + (unsigned)atomicAdd(&aux[d], 1);
            if (pos < ECAP) csr[pos] = (unsigned char)s;
        }
    }
    // X0 = z_table[z]; lo = 0
    for (int idx = t; idx < 8192; idx += 512) {
        int n = idx >> 6, c = idx & 63;
        int zv = z[(g << 7) + n];
        zv = (zv < 0) ? 0 : ((zv >= MAXZ) ? MAXZ - 1 : zv);
        Xhi[xh_idx(n, c)] = zt[zv * 64 + c];
    }
    for (int idx = t; idx < 4096; idx += 512) Xlo[idx] = 0u;
    __syncthreads();

    float g1p[2][16];   // fused conv1 partials (rank only permutes conv1 rows)
#pragma unroll
    for (int rw = 0; rw < 2; ++rw)
#pragma unroll
        for (int c = 0; c < 16; ++c) g1p[rw][c] = 0.f;

    // ---- three GCN layers ----
    for (int layer = 0; layer < 3; ++layer) {
        const float* Wg = (layer == 0) ? W0 : (layer == 1) ? W1 : W2;
        const float* bg = (layer == 0) ? b0 : (layer == 1) ? b1 : b2;

        // phase 1: acc = (X @ W)[rows r0,r1][c0..c0+7]
        double accd[2][8]; float accf[2][8];
#pragma unroll
        for (int rw = 0; rw < 2; ++rw)
#pragma unroll
            for (int j = 0; j < 8; ++j) { accd[rw][j] = 0.0; accf[rw][j] = 0.f; }

        for (int half = 0; half < 2; ++half) {
            __syncthreads();                                  // prior Wf readers done
            ((float4*)Wf)[t] = ((const float4*)(Wg + (half << 11)))[t];
            __syncthreads();
            for (int kk = 0; kk < 32; kk += 2) {
                int k = (half << 5) + kk;
                unsigned u0 = Xlo[xl_idx(r0, k >> 1)];
                unsigned u1 = Xlo[xl_idx(r1, k >> 1)];
#pragma unroll
                for (int kp = 0; kp < 2; ++kp) {
                    int kq = kk + kp;
                    float4 wa = *(const float4*)&Wf[(kq << 6) + c0];
                    float4 wb = *(const float4*)&Wf[(kq << 6) + c0 + 4];
                    float wf[8] = {wa.x, wa.y, wa.z, wa.w, wb.x, wb.y, wb.z, wb.w};
                    double x0 = (double)Xhi[xh_idx(r0, k + kp)];
                    double x1 = (double)Xhi[xh_idx(r1, k + kp)];
                    float  l0 = kp ? bfu_hi(u0) : bfu_lo(u0);
                    float  l1 = kp ? bfu_hi(u1) : bfu_lo(u1);
#pragma unroll
                    for (int j = 0; j < 8; ++j) {
                        double wd = (double)wf[j];
                        accd[0][j] += x0 * wd;
                        accd[1][j] += x1 * wd;
                        accf[0][j] = fmaf(l0, wf[j], accf[0][j]);
                        accf[1][j] = fmaf(l1, wf[j], accf[1][j]);
                    }
                }
            }
        }
        __syncthreads();                                      // all X reads done

        // H = dinv * acc; write hi/lo
        float hfv[2][8], rsv[2][8];
#pragma unroll
        for (int rw = 0; rw < 2; ++rw) {
            int rr = rw ? r1 : r0;
            double dv = rw ? dv1 : dv0;
#pragma unroll
            for (int j = 0; j < 8; ++j) {
                double h = dv * (accd[rw][j] + (double)accf[rw][j]);
                float hf = (float)h;
                hfv[rw][j] = hf;
                rsv[rw][j] = (float)(h - (double)hf);
            }
            int bi = xh_idx(rr, c0);
            *(float4*)&Xhi[bi]     = make_float4(hfv[rw][0], hfv[rw][1], hfv[rw][2], hfv[rw][3]);
            *(float4*)&Xhi[bi + 4] = make_float4(hfv[rw][4], hfv[rw][5], hfv[rw][6], hfv[rw][7]);
            uint4 lv;
            lv.x = packlo(rsv[rw][0], rsv[rw][1]);
            lv.y = packlo(rsv[rw][2], rsv[rw][3]);
            lv.z = packlo(rsv[rw][4], rsv[rw][5]);
            lv.w = packlo(rsv[rw][6], rsv[rw][7]);
            *(uint4*)&Xlo[xl_idx(rr, c0 >> 1)] = lv;
        }
        __syncthreads();                                      // H fully written

        // phase 2: agg = H[own] + sum_neighbors H[s]
        double ad[2][8]; float af[2][8];
#pragma unroll
        for (int rw = 0; rw < 2; ++rw)
#pragma unroll
            for (int j = 0; j < 8; ++j) { ad[rw][j] = (double)hfv[rw][j]; af[rw][j] = rsv[rw][j]; }

#pragma unroll
        for (int rw = 0; rw < 2; ++rw) {
            int rr = rw ? r1 : r0;
            for (unsigned e = rp16[rr]; e < rp16[rr + 1]; ++e) {
                int s = csr[e];
                int bi = (s << 6) | (c0 ^ ((s & 7) << 3));
                float4 a = *(const float4*)&Xhi[bi];
                float4 b = *(const float4*)&Xhi[bi + 4];
                uint4 lu = *(const uint4*)&Xlo[(s << 5) | ((c0 >> 1) ^ ((s & 7) << 2))];
                ad[rw][0] += (double)a.x; ad[rw][1] += (double)a.y;
                ad[rw][2] += (double)a.z; ad[rw][3] += (double)a.w;
                ad[rw][4] += (double)b.x; ad[rw][5] += (double)b.y;
                ad[rw][6] += (double)b.z; ad[rw][7] += (double)b.w;
                af[rw][0] += bfu_lo(lu.x); af[rw][1] += bfu_hi(lu.x);
                af[rw][2] += bfu_lo(lu.y); af[rw][3] += bfu_hi(lu.y);
                af[rw][4] += bfu_lo(lu.z); af[rw][5] += bfu_hi(lu.z);
                af[rw][6] += bfu_lo(lu.w); af[rw][7] += bfu_hi(lu.w);
            }
        }
        __syncthreads();                                      // all H reads done

        // X = tanh(dinv*agg + b); write hi/lo; accumulate conv1 partials
        float vf[2][8];
#pragma unroll
        for (int rw = 0; rw < 2; ++rw) {
            int rr = rw ? r1 : r0;
            double dv = rw ? dv1 : dv0;
            float rs[8];
#pragma unroll
            for (int j = 0; j < 8; ++j) {
                double v = tanh(dv * (ad[rw][j] + (double)af[rw][j]) + (double)bg[c0 + j]);
                float vfl = (float)v;
                vf[rw][j] = vfl;
                rs[j] = (float)(v - (double)vfl);
            }
            int bi = xh_idx(rr, c0);
            *(float4*)&Xhi[bi]     = make_float4(vf[rw][0], vf[rw][1], vf[rw][2], vf[rw][3]);
            *(float4*)&Xhi[bi + 4] = make_float4(vf[rw][4], vf[rw][5], vf[rw][6], vf[rw][7]);
            uint4 lv;
            lv.x = packlo(rs[0], rs[1]);
            lv.y = packlo(rs[2], rs[3]);
            lv.z = packlo(rs[4], rs[5]);
            lv.w = packlo(rs[6], rs[7]);
            *(uint4*)&Xlo[xl_idx(rr, c0 >> 1)] = lv;
        }
        const float* w1base = c1w + layer * 64 + c0;
        for (int c = 0; c < 16; ++c) {
            const float* wr = w1base + c * 193;
#pragma unroll
            for (int j = 0; j < 8; ++j) {
                float wv = wr[j];
                g1p[0][c] = fmaf(vf[0][j], wv, g1p[0][c]);
                g1p[1][c] = fmaf(vf[1][j], wv, g1p[1][c]);
            }
        }
        __syncthreads();
    }

    // ---- layer 4 (64->1): key path ----
    if (t < 128) {
        double sd = 0.0; float sf = 0.f;
        for (int k = 0; k < 64; k += 2) {
            unsigned u = Xlo[xl_idx(t, k >> 1)];
            float wA = W3[k], wB = W3[k + 1];
            sd += (double)Xhi[xh_idx(t, k)] * (double)wA
                + (double)Xhi[xh_idx(t, k + 1)] * (double)wB;
            sf = fmaf(bfu_lo(u), wA, sf);
            sf = fmaf(bfu_hi(u), wB, sf);
        }
        h4s[t] = (1.0 / sqrt((double)(mydeg + 1))) * (sd + (double)sf);
    }
    __syncthreads();
    if (t < 128) {
        double a = h4s[t];
        for (unsigned e = rp16[t]; e < rp16[t + 1]; ++e) a += h4s[csr[e]];
        keyd[t] = tanh((1.0 / sqrt((double)(mydeg + 1))) * a + (double)b3[0]);
    }
    __syncthreads();

    // stable descending rank == stable argsort(-key); inverse map for top-30
    if (t < 128) {
        double kv = keyd[t];
        int rk = 0;
        for (int j = 0; j < 128; ++j) {
            double kj = keyd[j];
            if (kj > kv || (kj == kv && j < t)) ++rk;
        }
        aux[t] = rk;
        if (rk < 30) inv[rk] = t;
    }

    // reduce conv1 partials across the 8 channel-lanes; write G1 into Wf (free now)
#pragma unroll
    for (int m = 1; m <= 4; m <<= 1) {
#pragma unroll
        for (int rw = 0; rw < 2; ++rw)
#pragma unroll
            for (int c = 0; c < 16; ++c)
                g1p[rw][c] += __shfl_xor(g1p[rw][c], m, 64);
    }
    __syncthreads();
    float* G1 = Wf;   // [node][16]
    if ((t & 7) == 0) {
#pragma unroll
        for (int c = 0; c < 16; c += 4) {
            *(float4*)&G1[r0 * 16 + c] = make_float4(g1p[0][c], g1p[0][c + 1], g1p[0][c + 2], g1p[0][c + 3]);
            *(float4*)&G1[r1 * 16 + c] = make_float4(g1p[1][c], g1p[1][c + 1], g1p[1][c + 2], g1p[1][c + 3]);
        }
    }
    __syncthreads();

    // ---- head ----
    float* h1v = (float*)Xlo;          // 480
    float* ppv = h1v + 480;            // 240
    float* flv = ppv + 240;            // 352
    float* hmv = flv + 352;            // 128

    if (t < 480) {
        int c = t & 15, k = t >> 4;
        int node = inv[k];
        float s = G1[node * 16 + c] + c1w[c * 193 + 192] * (float)keyd[node] + c1b[c];
        h1v[c * 30 + k] = s > 0.f ? s : 0.f;
    }
    __syncthreads();
    if (t < 240) {
        int c = t & 15, i = t >> 4;
        float a = h1v[c * 30 + 2 * i], b = h1v[c * 30 + 2 * i + 1];
        ppv[c * 15 + i] = a > b ? a : b;
    }
    __syncthreads();
    if (t < 352) {
        int o = t / 11, j = t % 11;
        float s = c2b[o];
        for (int i = 0; i < 16; ++i)
#pragma unroll
            for (int u = 0; u < 5; ++u)
                s = fmaf(ppv[i * 15 + j + u], c2w[o * 80 + i * 5 + u], s);
        flv[t] = s > 0.f ? s : 0.f;
    }
    __syncthreads();
    if (t < 128) {
        float s = l1b[t];
        for (int i = 0; i < 352; ++i) s = fmaf(flv[i], l1w[i * 128 + t], s);
        hmv[t] = s > 0.f ? s : 0.f;
    }
    __syncthreads();
    if (t < 64) {
        float v = fmaf(hmv[t], l2w[t], hmv[t + 64] * l2w[t + 64]);
#pragma unroll
        for (int o = 32; o > 0; o >>= 1) v += __shfl_down(v, o, 64);
        if (t == 0) out[g] = v + l2b[0];
    }
}

// ---------------- launch ----------------

extern "C" void kernel_launch(void* const* d_in, const int* in_sizes, int n_in,
                              void* d_out, int out_size, void* d_ws, size_t ws_size,
                              hipStream_t stream) {
    const int*   z   = (const int*)d_in[0];
    const int*   ei  = (const int*)d_in[1];
    const float* zt  = (const float*)d_in[3];
    const float* W0  = (const float*)d_in[4];
    const float* b0  = (const float*)d_in[5];
    const float* W1  = (const float*)d_in[6];
    const float* b1  = (const float*)d_in[7];
    const float* W2  = (const float*)d_in[8];
    const float* b2  = (const float*)d_in[9];
    const float* W3  = (const float*)d_in[10];
    const float* b3  = (const float*)d_in[11];
    const float* c1w = (const float*)d_in[12];
    const float* c1b = (const float*)d_in[13];
    const float* c2w = (const float*)d_in[14];
    const float* c2b = (const float*)d_in[15];
    const float* l1w = (const float*)d_in[16];
    const float* l1b = (const float*)d_in[17];
    const float* l2w = (const float*)d_in[18];
    const float* l2b = (const float*)d_in[19];
    float* out = (float*)d_out;

    const size_t ECNT_B = (size_t)NGRAPH * NB * 4;                   // 64 KB
    const size_t NEEDED = ECNT_B + (size_t)NGRAPH * NB * CAPB * 2;   // ~6.9 MB
    if (ws_size < NEEDED) {
        markWS_kernel<<<4, 256, 0, stream>>>(out);
        return;
    }

    unsigned*       ecnt  = (unsigned*)d_ws;
    unsigned short* edges = (unsigned short*)((char*)d_ws + ECNT_B);

    hipMemsetAsync(ecnt, 0, ECNT_B, stream);
    bscatter_kernel<<<(E_EDGES + 255) / 256, 256, 0, stream>>>(ei, ecnt, edges);

    gnn_kernel<<<NGRAPH, 512, 0, stream>>>(z, ecnt, edges, zt,
                                           W0, b0, W1, b1, W2, b2, W3, b3,
                                           c1w, c1b, c2w, c2b, l1w, l1b, l2w, l2b,
                                           out);
}